// Round 8
// baseline (99.770 us; speedup 1.0000x reference)
//
#include <hip/hip_runtime.h>

// HyperLinear, 2-kernel split (Bb intermediate eliminated):
//  gemm1: blocks 0..287: G[2048][576] bf16 = bf16(x) @ Bb^T where the B-panel
//         is built on the fly in LDS:
//           rows [0,512):  transpose of fcwp_w (Bb[n][i] = fcwp_w[i*512+n])
//           rows [512,576): c[m][i] = fcwp_b[i*64+m] + fcwi_b[..] + index·fcwi_w[..]
//         blocks 288..308: build B2[256][352] bf16
//         (target_w | fcwe_w | fcbp_w | fcwe_b | bias_const | 0).
//  gemm2: out[2048][256] f32 = [x | t | h | sx | 1 | 0] @ B2^T, A-panel built
//         in LDS; t folded from G (t[s][m] = sum_p h[s][p]*G[s][m*8+p] + G[s][512+m]).

#define B_TOT 2048
#define NP    8
#define CIN   256
#define COUT  256
#define MID   64
#define K2    352
#define LDG   576
#define LDAS  136
#define LDA2S 360
#define LDB2S 360

typedef short  short8  __attribute__((ext_vector_type(8)));
typedef float  floatx4 __attribute__((ext_vector_type(4)));

__device__ __forceinline__ unsigned short f2bf(float f) {
    union { float f; unsigned u; } v; v.f = f;
    unsigned r = v.u + 0x7FFFu + ((v.u >> 16) & 1u);
    return (unsigned short)(r >> 16);
}
__device__ __forceinline__ float bf2f(unsigned short u) {
    union { unsigned u; float f; } v; v.u = ((unsigned)u) << 16;
    return v.f;
}

// ------- gemm1 (blocks 0..287, B-panel built in-block) + B2 build (288..308) -------
__global__ __launch_bounds__(256) void gemm1_kernel(
    const float* __restrict__ x,             // [2048][256]
    const float* __restrict__ index,
    const float* __restrict__ fcwp_w, const float* __restrict__ fcwp_b,
    const float* __restrict__ fcwi_w, const float* __restrict__ fcwi_b,
    const float* __restrict__ target_w, const float* __restrict__ target_b,
    const float* __restrict__ fcwe_w, const float* __restrict__ fcwe_b,
    const float* __restrict__ fcbp_w, const float* __restrict__ fcbp_b,
    const float* __restrict__ fcbi_w, const float* __restrict__ fcbi_b,
    unsigned short* __restrict__ B2,         // [256][352]
    unsigned short* __restrict__ G)          // [2048][576] bf16
{
    __shared__ unsigned short As[64 * LDAS];   // 17408 B
    __shared__ unsigned short Bs[64 * LDAS];   // 17408 B
    const int blk = blockIdx.x, tid = threadIdx.x;

    if (blk < 288) {
        const int lane = tid & 63, w = tid >> 6;
        const int col = lane & 15, quad = lane >> 4;
        const int mb = (blk & 31) * 64, g = blk >> 5, nb = g * 64;
        const float i0 = index[0], i1 = index[1], i2 = index[2], i3 = index[3];

        floatx4 acc[4] = {floatx4{0,0,0,0}, floatx4{0,0,0,0},
                          floatx4{0,0,0,0}, floatx4{0,0,0,0}};

        for (int kh = 0; kh < 2; ++kh) {
            const int k0 = kh * 128;
            __syncthreads();
            // stage As: x fp32 -> bf16, 64 rows x 128 cols
            #pragma unroll
            for (int it = 0; it < 8; ++it) {
                int idx = it * 256 + tid;
                int r = idx >> 5, c = (idx & 31) * 4;
                float4 v = *(const float4*)(x + (size_t)(mb + r) * CIN + k0 + c);
                ushort4 o4;
                o4.x = f2bf(v.x); o4.y = f2bf(v.y); o4.z = f2bf(v.z); o4.w = f2bf(v.w);
                *(ushort4*)&As[r * LDAS + c] = o4;
            }
            // stage Bs (build B-panel in place)
            if (g < 8) {
                // Bs[n][i] = bf16(fcwp_w[(k0+i)*512 + nb + n]) — scatter transpose
                #pragma unroll
                for (int it = 0; it < 8; ++it) {
                    int idx = it * 256 + tid;
                    int r = idx >> 4, c = (idx & 15) * 4;   // r = i_local, c = n_local
                    float4 v = *(const float4*)(fcwp_w + (size_t)(k0 + r) * 512 + nb + c);
                    Bs[(c + 0) * LDAS + r] = f2bf(v.x);
                    Bs[(c + 1) * LDAS + r] = f2bf(v.y);
                    Bs[(c + 2) * LDAS + r] = f2bf(v.z);
                    Bs[(c + 3) * LDAS + r] = f2bf(v.w);
                }
            } else {
                // c rows: Bs[m][i] = bf16(fcwp_b[e]+fcwi_b[e]+index·fcwi_w[e,:]), e=(k0+i)*64+m
                #pragma unroll
                for (int it = 0; it < 8; ++it) {
                    int idx = it * 256 + tid;
                    int r = idx >> 4, c = (idx & 15) * 4;   // r = i_local, c = m
                    int e = (k0 + r) * 64 + c;
                    float4 pb = *(const float4*)(fcwp_b + e);
                    float4 ib = *(const float4*)(fcwi_b + e);
                    float4 w0 = *(const float4*)(fcwi_w + (size_t)e * 4);
                    float4 w1 = *(const float4*)(fcwi_w + (size_t)(e + 1) * 4);
                    float4 w2 = *(const float4*)(fcwi_w + (size_t)(e + 2) * 4);
                    float4 w3 = *(const float4*)(fcwi_w + (size_t)(e + 3) * 4);
                    Bs[(c + 0) * LDAS + r] = f2bf(pb.x + ib.x + i0*w0.x + i1*w0.y + i2*w0.z + i3*w0.w);
                    Bs[(c + 1) * LDAS + r] = f2bf(pb.y + ib.y + i0*w1.x + i1*w1.y + i2*w1.z + i3*w1.w);
                    Bs[(c + 2) * LDAS + r] = f2bf(pb.z + ib.z + i0*w2.x + i1*w2.y + i2*w2.z + i3*w2.w);
                    Bs[(c + 3) * LDAS + r] = f2bf(pb.w + ib.w + i0*w3.x + i1*w3.y + i2*w3.z + i3*w3.w);
                }
            }
            __syncthreads();
            #pragma unroll
            for (int ks = 0; ks < 4; ++ks) {
                int kc = ks * 32 + quad * 8;
                short8 af = *(const short8*)&As[(w * 16 + col) * LDAS + kc];
                #pragma unroll
                for (int f = 0; f < 4; ++f) {
                    short8 bfr = *(const short8*)&Bs[(f * 16 + col) * LDAS + kc];
                    acc[f] = __builtin_amdgcn_mfma_f32_16x16x32_bf16(af, bfr, acc[f], 0, 0, 0);
                }
            }
        }
        #pragma unroll
        for (int f = 0; f < 4; ++f)
            #pragma unroll
            for (int r = 0; r < 4; ++r)
                G[(size_t)(mb + w * 16 + quad * 4 + r) * LDG + nb + f * 16 + col]
                    = f2bf(acc[f][r]);
    } else if (blk < 304) {
        // B2 cols [0,256) = target_w
        int base = (blk - 288) * 4096;
        #pragma unroll
        for (int k = 0; k < 4; ++k) {
            int e = base + k * 1024 + tid * 4;
            int o = e >> 8, c = e & 255;
            float4 v = *(const float4*)(target_w + e);
            ushort4 o4;
            o4.x = f2bf(v.x); o4.y = f2bf(v.y); o4.z = f2bf(v.z); o4.w = f2bf(v.w);
            *(ushort4*)&B2[(size_t)o * K2 + c] = o4;
        }
    } else if (blk < 308) {
        // B2 cols [256,320) = fcwe_w
        int base = (blk - 304) * 4096;
        #pragma unroll
        for (int k = 0; k < 4; ++k) {
            int e = base + k * 1024 + tid * 4;
            int o = e >> 6, m = e & 63;
            float4 v = *(const float4*)(fcwe_w + e);
            ushort4 o4;
            o4.x = f2bf(v.x); o4.y = f2bf(v.y); o4.z = f2bf(v.z); o4.w = f2bf(v.w);
            *(ushort4*)&B2[(size_t)o * K2 + 256 + m] = o4;
        }
    } else {
        // B2 tail per output o
        int o = tid;
        size_t bo = (size_t)o * K2;
        float4 p0 = *(const float4*)(fcbp_w + (size_t)o * 8);
        float4 p1 = *(const float4*)(fcbp_w + (size_t)o * 8 + 4);
        B2[bo + 320] = f2bf(p0.x); B2[bo + 321] = f2bf(p0.y);
        B2[bo + 322] = f2bf(p0.z); B2[bo + 323] = f2bf(p0.w);
        B2[bo + 324] = f2bf(p1.x); B2[bo + 325] = f2bf(p1.y);
        B2[bo + 326] = f2bf(p1.z); B2[bo + 327] = f2bf(p1.w);
        B2[bo + 328] = f2bf(fcwe_b[o]);
        float bc = target_b[o] + fcbp_b[o] + fcbi_b[o]
                 + index[0] * fcbi_w[o * 4]     + index[1] * fcbi_w[o * 4 + 1]
                 + index[2] * fcbi_w[o * 4 + 2] + index[3] * fcbi_w[o * 4 + 3];
        B2[bo + 329] = f2bf(bc);
        #pragma unroll
        for (int z = 330; z < K2; ++z) B2[bo + z] = 0;
    }
}

// ------- gemm2: out = [x|t|h|sx|1|0] @ B2^T, A-panel built in LDS -------
__global__ __launch_bounds__(256) void gemm2_kernel(
    const float* __restrict__ x,             // [2048][256]
    const float* __restrict__ h,             // [2048][8]
    const unsigned short* __restrict__ B2,   // [256][352]
    const unsigned short* __restrict__ G,    // [2048][576]
    float* __restrict__ out)                 // [2048][256]
{
    __shared__ unsigned short As[32 * LDA2S];   // 23040 B
    __shared__ unsigned short Bs[64 * LDB2S];   // 46080 B
    __shared__ float red[32][8];

    const int tid = threadIdx.x, lane = tid & 63, w = tid >> 6;
    const int col = lane & 15, quad = lane >> 4;
    const int b0 = blockIdx.x * 32, n0 = blockIdx.y * 64;

    // stage As x-cols [0,256): fp32 -> bf16
    #pragma unroll
    for (int it = 0; it < 8; ++it) {
        int idx = it * 256 + tid;
        int r = idx >> 6, c = (idx & 63) * 4;
        float4 v = *(const float4*)(x + (size_t)(b0 + r) * CIN + c);
        ushort4 o4;
        o4.x = f2bf(v.x); o4.y = f2bf(v.y); o4.z = f2bf(v.z); o4.w = f2bf(v.w);
        *(ushort4*)&As[r * LDA2S + c] = o4;
    }
    // h cols [320,328)
    {
        int s = tid >> 3, p = tid & 7;
        As[s * LDA2S + 320 + p] = f2bf(h[(size_t)(b0 + s) * NP + p]);
    }
    // sx partials (fp32 from global x)
    {
        int s = tid >> 3, seg = tid & 7;
        const float* xr = x + (size_t)(b0 + s) * CIN + seg * 32;
        float p = 0.f;
        #pragma unroll
        for (int k = 0; k < 8; ++k) {
            float4 v = *(const float4*)(xr + k * 4);
            p += v.x + v.y + v.z + v.w;
        }
        red[s][seg] = p;
    }
    // zero cols [330,352)
    for (int idx = tid; idx < 32 * 22; idx += 256) {
        int s = idx / 22, c = 330 + idx % 22;
        As[s * LDA2S + c] = 0;
    }
    // stage Bs: 64 rows x 352
    #pragma unroll
    for (int it = 0; it < 11; ++it) {
        int idx = it * 256 + tid;
        int r = idx / 44, c = (idx % 44) * 8;
        *(uint4*)&Bs[r * LDB2S + c] =
            *(const uint4*)(B2 + (size_t)(n0 + r) * K2 + c);
    }
    // fold t[s][m] into As cols [256,320)
    {
        int s = tid >> 3, mg = tid & 7;
        const unsigned short* grow = G + (size_t)(b0 + s) * LDG;
        float4 h0 = *(const float4*)(h + (size_t)(b0 + s) * NP);
        float4 h1 = *(const float4*)(h + (size_t)(b0 + s) * NP + 4);
        float hv[8] = {h0.x, h0.y, h0.z, h0.w, h1.x, h1.y, h1.z, h1.w};
        ushort4 cu0 = *(const ushort4*)(grow + 512 + mg * 8);
        ushort4 cu1 = *(const ushort4*)(grow + 512 + mg * 8 + 4);
        float t[8] = {bf2f(cu0.x), bf2f(cu0.y), bf2f(cu0.z), bf2f(cu0.w),
                      bf2f(cu1.x), bf2f(cu1.y), bf2f(cu1.z), bf2f(cu1.w)};
        #pragma unroll
        for (int j = 0; j < 8; ++j) {
            const unsigned short* gp = grow + (mg * 8 + j) * 8;
            ushort4 g0 = *(const ushort4*)gp;
            ushort4 g1 = *(const ushort4*)(gp + 4);
            t[j] += hv[0] * bf2f(g0.x) + hv[1] * bf2f(g0.y)
                  + hv[2] * bf2f(g0.z) + hv[3] * bf2f(g0.w)
                  + hv[4] * bf2f(g1.x) + hv[5] * bf2f(g1.y)
                  + hv[6] * bf2f(g1.z) + hv[7] * bf2f(g1.w);
        }
        ushort4 t0, t1;
        t0.x = f2bf(t[0]); t0.y = f2bf(t[1]); t0.z = f2bf(t[2]); t0.w = f2bf(t[3]);
        t1.x = f2bf(t[4]); t1.y = f2bf(t[5]); t1.z = f2bf(t[6]); t1.w = f2bf(t[7]);
        *(ushort4*)&As[s * LDA2S + 256 + mg * 8]     = t0;
        *(ushort4*)&As[s * LDA2S + 256 + mg * 8 + 4] = t1;
    }
    __syncthreads();
    // sx + ones into As cols 328/329
    if (tid < 32) {
        float s = red[tid][0] + red[tid][1] + red[tid][2] + red[tid][3]
                + red[tid][4] + red[tid][5] + red[tid][6] + red[tid][7];
        As[tid * LDA2S + 328] = f2bf(s);
        As[tid * LDA2S + 329] = 0x3F80;   // 1.0 bf16
    }
    __syncthreads();

    const int mr = (w & 1) * 16, nbw = (w >> 1) * 32;
    floatx4 acc[2] = {floatx4{0,0,0,0}, floatx4{0,0,0,0}};
    #pragma unroll
    for (int ks = 0; ks < 11; ++ks) {
        int kc = ks * 32 + quad * 8;
        short8 af = *(const short8*)&As[(mr + col) * LDA2S + kc];
        #pragma unroll
        for (int f = 0; f < 2; ++f) {
            short8 bfr = *(const short8*)&Bs[(nbw + f * 16 + col) * LDB2S + kc];
            acc[f] = __builtin_amdgcn_mfma_f32_16x16x32_bf16(af, bfr, acc[f], 0, 0, 0);
        }
    }
    #pragma unroll
    for (int f = 0; f < 2; ++f)
        #pragma unroll
        for (int r = 0; r < 4; ++r)
            out[(size_t)(b0 + mr + quad * 4 + r) * COUT + n0 + nbw + f * 16 + col]
                = acc[f][r];
}

extern "C" void kernel_launch(void* const* d_in, const int* in_sizes, int n_in,
                              void* d_out, int out_size, void* d_ws, size_t ws_size,
                              hipStream_t stream) {
    const float* x        = (const float*)d_in[0];
    const float* h        = (const float*)d_in[1];
    const float* index    = (const float*)d_in[2];
    const float* target_w = (const float*)d_in[3];
    const float* target_b = (const float*)d_in[4];
    const float* fcwp_w   = (const float*)d_in[5];
    const float* fcwp_b   = (const float*)d_in[6];
    const float* fcwi_w   = (const float*)d_in[7];
    const float* fcwi_b   = (const float*)d_in[8];
    const float* fcwe_w   = (const float*)d_in[9];
    const float* fcwe_b   = (const float*)d_in[10];
    const float* fcbp_w   = (const float*)d_in[11];
    const float* fcbp_b   = (const float*)d_in[12];
    const float* fcbi_w   = (const float*)d_in[13];
    const float* fcbi_b   = (const float*)d_in[14];
    float* out = (float*)d_out;

    char* ws = (char*)d_ws;
    unsigned short* B2 = (unsigned short*)ws;               // 256*352*2 = 180224
    unsigned short* G  = (unsigned short*)(ws + 180224);    // 2048*576*2 = 2359296

    gemm1_kernel<<<309, 256, 0, stream>>>(
        x, index, fcwp_w, fcwp_b, fcwi_w, fcwi_b,
        target_w, target_b, fcwe_w, fcwe_b,
        fcbp_w, fcbp_b, fcbi_w, fcbi_b, B2, G);

    gemm2_kernel<<<dim3(B_TOT / 32, COUT / 64), 256, 0, stream>>>(
        x, h, B2, G, out);
}

// Round 9
// 95.212 us; speedup vs baseline: 1.0479x; 1.0479x over previous
//
#include <hip/hip_runtime.h>

// HyperLinear, lean 3-kernel split (best-known config, r7):
//  setup_bb:  Bb[576][256] bf16 (512 permuted fcwp_w rows + 64 c-rows). 36 blocks.
//  gemm1:     blocks 0..287: G[2048][576] bf16 = bf16(x) @ Bb^T (64x64 tiles,
//             x converted fp32->bf16 during LDS staging).
//             blocks 288..308: build B2[256][352] bf16
//             (target_w | fcwe_w | fcbp_w | fcwe_b | bias_const | 0).
//  gemm2:     out[2048][256] f32 = [x | t | h | sx | 1 | 0] @ B2^T, with the
//             A-panel built entirely in LDS: x converted in staging, t folded
//             from G (t[s][m] = sum_p h[s][p]*G[s][m*8+p] + G[s][512+m]),
//             sx = row-sum of x, h read fp32.

#define B_TOT 2048
#define NP    8
#define CIN   256
#define COUT  256
#define MID   64
#define K2    352
#define LDG   576
#define LDAS  136
#define LDA2S 360
#define LDB2S 360

typedef short  short8  __attribute__((ext_vector_type(8)));
typedef float  floatx4 __attribute__((ext_vector_type(4)));

__device__ __forceinline__ unsigned short f2bf(float f) {
    union { float f; unsigned u; } v; v.f = f;
    unsigned r = v.u + 0x7FFFu + ((v.u >> 16) & 1u);
    return (unsigned short)(r >> 16);
}
__device__ __forceinline__ float bf2f(unsigned short u) {
    union { unsigned u; float f; } v; v.u = ((unsigned)u) << 16;
    return v.f;
}

// ---------------- setup: Bb only (36 blocks) ----------------
__global__ __launch_bounds__(256) void setup_bb(
    const float* __restrict__ index,
    const float* __restrict__ fcwp_w, const float* __restrict__ fcwp_b,
    const float* __restrict__ fcwi_w, const float* __restrict__ fcwi_b,
    unsigned short* __restrict__ Bb)
{
    __shared__ unsigned short Lt[64][68];
    const int blk = blockIdx.x, tid = threadIdx.x;

    if (blk < 32) {
        // Bb[n][i] = bf16(fcwp_w[i*512+n]); 64x64 tile transpose
        const int i0 = (blk >> 3) * 64, n0 = (blk & 7) * 64;
        const int r = tid >> 4, c4 = (tid & 15) * 4;
        #pragma unroll
        for (int k = 0; k < 4; ++k) {
            int ii = r + k * 16;
            float4 v = *(const float4*)(fcwp_w + (size_t)(i0 + ii) * 512 + n0 + c4);
            Lt[c4 + 0][ii] = f2bf(v.x); Lt[c4 + 1][ii] = f2bf(v.y);
            Lt[c4 + 2][ii] = f2bf(v.z); Lt[c4 + 3][ii] = f2bf(v.w);
        }
        __syncthreads();
        const int nn = tid >> 2, ic0 = (tid & 3) * 16;
        #pragma unroll
        for (int k = 0; k < 4; ++k) {
            int ic = ic0 + k * 4;
            ushort4 o4;
            o4.x = Lt[nn][ic]; o4.y = Lt[nn][ic + 1];
            o4.z = Lt[nn][ic + 2]; o4.w = Lt[nn][ic + 3];
            *(ushort4*)&Bb[(size_t)(n0 + nn) * CIN + i0 + ic] = o4;
        }
    } else {
        // c rows: Bb[512+m][i], e = i*64+m
        const int i0 = (blk - 32) * 64;
        const float x0 = index[0], x1 = index[1], x2 = index[2], x3 = index[3];
        const int r = tid >> 4, c4 = (tid & 15) * 4;
        #pragma unroll
        for (int k = 0; k < 4; ++k) {
            int ii = r + k * 16;
            int e = (i0 + ii) * 64 + c4;
            float4 pb = *(const float4*)(fcwp_b + e);
            float4 ib = *(const float4*)(fcwi_b + e);
            float pbv[4] = {pb.x, pb.y, pb.z, pb.w};
            float ibv[4] = {ib.x, ib.y, ib.z, ib.w};
            #pragma unroll
            for (int j = 0; j < 4; ++j) {
                float4 wv = *(const float4*)(fcwi_w + (size_t)(e + j) * 4);
                Lt[c4 + j][ii] = f2bf(pbv[j] + ibv[j]
                    + x0 * wv.x + x1 * wv.y + x2 * wv.z + x3 * wv.w);
            }
        }
        __syncthreads();
        const int mm = tid >> 2, ic0 = (tid & 3) * 16;
        #pragma unroll
        for (int k = 0; k < 4; ++k) {
            int ic = ic0 + k * 4;
            ushort4 o4;
            o4.x = Lt[mm][ic]; o4.y = Lt[mm][ic + 1];
            o4.z = Lt[mm][ic + 2]; o4.w = Lt[mm][ic + 3];
            *(ushort4*)&Bb[(size_t)(512 + mm) * CIN + i0 + ic] = o4;
        }
    }
}

// ------- gemm1 (blocks 0..287) + B2 build (blocks 288..308) -------
__global__ __launch_bounds__(256) void gemm1_kernel(
    const float* __restrict__ x,             // [2048][256]
    const unsigned short* __restrict__ Bb,   // [576][256]
    const float* __restrict__ index,
    const float* __restrict__ target_w, const float* __restrict__ target_b,
    const float* __restrict__ fcwe_w, const float* __restrict__ fcwe_b,
    const float* __restrict__ fcbp_w, const float* __restrict__ fcbp_b,
    const float* __restrict__ fcbi_w, const float* __restrict__ fcbi_b,
    unsigned short* __restrict__ B2,         // [256][352]
    unsigned short* __restrict__ G)          // [2048][576] bf16
{
    __shared__ unsigned short As[64 * LDAS];
    __shared__ unsigned short Bs[64 * LDAS];
    const int blk = blockIdx.x, tid = threadIdx.x;

    if (blk < 288) {
        const int lane = tid & 63, w = tid >> 6;
        const int col = lane & 15, quad = lane >> 4;
        const int mb = (blk & 31) * 64, nb = (blk >> 5) * 64;

        floatx4 acc[4] = {floatx4{0,0,0,0}, floatx4{0,0,0,0},
                          floatx4{0,0,0,0}, floatx4{0,0,0,0}};

        for (int kh = 0; kh < 2; ++kh) {
            const int k0 = kh * 128;
            __syncthreads();
            // stage As: x fp32 -> bf16, 64 rows x 128 cols
            #pragma unroll
            for (int it = 0; it < 8; ++it) {
                int idx = it * 256 + tid;
                int r = idx >> 5, c = (idx & 31) * 4;
                float4 v = *(const float4*)(x + (size_t)(mb + r) * CIN + k0 + c);
                ushort4 o4;
                o4.x = f2bf(v.x); o4.y = f2bf(v.y); o4.z = f2bf(v.z); o4.w = f2bf(v.w);
                *(ushort4*)&As[r * LDAS + c] = o4;
            }
            // stage Bs from Bb (bf16 copy)
            #pragma unroll
            for (int it = 0; it < 4; ++it) {
                int idx = it * 256 + tid;
                int r = idx >> 4, c = (idx & 15) * 8;
                *(uint4*)&Bs[r * LDAS + c] =
                    *(const uint4*)(Bb + (size_t)(nb + r) * CIN + k0 + c);
            }
            __syncthreads();
            #pragma unroll
            for (int ks = 0; ks < 4; ++ks) {
                int kc = ks * 32 + quad * 8;
                short8 af = *(const short8*)&As[(w * 16 + col) * LDAS + kc];
                #pragma unroll
                for (int f = 0; f < 4; ++f) {
                    short8 bfr = *(const short8*)&Bs[(f * 16 + col) * LDAS + kc];
                    acc[f] = __builtin_amdgcn_mfma_f32_16x16x32_bf16(af, bfr, acc[f], 0, 0, 0);
                }
            }
        }
        #pragma unroll
        for (int f = 0; f < 4; ++f)
            #pragma unroll
            for (int r = 0; r < 4; ++r)
                G[(size_t)(mb + w * 16 + quad * 4 + r) * LDG + nb + f * 16 + col]
                    = f2bf(acc[f][r]);
    } else if (blk < 304) {
        // B2 cols [0,256) = target_w
        int base = (blk - 288) * 4096;
        #pragma unroll
        for (int k = 0; k < 4; ++k) {
            int e = base + k * 1024 + tid * 4;
            int o = e >> 8, c = e & 255;
            float4 v = *(const float4*)(target_w + e);
            ushort4 o4;
            o4.x = f2bf(v.x); o4.y = f2bf(v.y); o4.z = f2bf(v.z); o4.w = f2bf(v.w);
            *(ushort4*)&B2[(size_t)o * K2 + c] = o4;
        }
    } else if (blk < 308) {
        // B2 cols [256,320) = fcwe_w
        int base = (blk - 304) * 4096;
        #pragma unroll
        for (int k = 0; k < 4; ++k) {
            int e = base + k * 1024 + tid * 4;
            int o = e >> 6, m = e & 63;
            float4 v = *(const float4*)(fcwe_w + e);
            ushort4 o4;
            o4.x = f2bf(v.x); o4.y = f2bf(v.y); o4.z = f2bf(v.z); o4.w = f2bf(v.w);
            *(ushort4*)&B2[(size_t)o * K2 + 256 + m] = o4;
        }
    } else {
        // B2 tail per output o
        int o = tid;
        size_t bo = (size_t)o * K2;
        float4 p0 = *(const float4*)(fcbp_w + (size_t)o * 8);
        float4 p1 = *(const float4*)(fcbp_w + (size_t)o * 8 + 4);
        B2[bo + 320] = f2bf(p0.x); B2[bo + 321] = f2bf(p0.y);
        B2[bo + 322] = f2bf(p0.z); B2[bo + 323] = f2bf(p0.w);
        B2[bo + 324] = f2bf(p1.x); B2[bo + 325] = f2bf(p1.y);
        B2[bo + 326] = f2bf(p1.z); B2[bo + 327] = f2bf(p1.w);
        B2[bo + 328] = f2bf(fcwe_b[o]);
        float bc = target_b[o] + fcbp_b[o] + fcbi_b[o]
                 + index[0] * fcbi_w[o * 4]     + index[1] * fcbi_w[o * 4 + 1]
                 + index[2] * fcbi_w[o * 4 + 2] + index[3] * fcbi_w[o * 4 + 3];
        B2[bo + 329] = f2bf(bc);
        #pragma unroll
        for (int z = 330; z < K2; ++z) B2[bo + z] = 0;
    }
}

// ------- gemm2: out = [x|t|h|sx|1|0] @ B2^T, A-panel built in LDS -------
__global__ __launch_bounds__(256) void gemm2_kernel(
    const float* __restrict__ x,             // [2048][256]
    const float* __restrict__ h,             // [2048][8]
    const unsigned short* __restrict__ B2,   // [256][352]
    const unsigned short* __restrict__ G,    // [2048][576]
    float* __restrict__ out)                 // [2048][256]
{
    __shared__ unsigned short As[32 * LDA2S];   // 23040 B
    __shared__ unsigned short Bs[64 * LDB2S];   // 46080 B
    __shared__ float red[32][8];

    const int tid = threadIdx.x, lane = tid & 63, w = tid >> 6;
    const int col = lane & 15, quad = lane >> 4;
    const int b0 = blockIdx.x * 32, n0 = blockIdx.y * 64;

    // stage As x-cols [0,256): fp32 -> bf16
    #pragma unroll
    for (int it = 0; it < 8; ++it) {
        int idx = it * 256 + tid;
        int r = idx >> 6, c = (idx & 63) * 4;
        float4 v = *(const float4*)(x + (size_t)(b0 + r) * CIN + c);
        ushort4 o4;
        o4.x = f2bf(v.x); o4.y = f2bf(v.y); o4.z = f2bf(v.z); o4.w = f2bf(v.w);
        *(ushort4*)&As[r * LDA2S + c] = o4;
    }
    // h cols [320,328)
    {
        int s = tid >> 3, p = tid & 7;
        As[s * LDA2S + 320 + p] = f2bf(h[(size_t)(b0 + s) * NP + p]);
    }
    // sx partials (fp32 from global x)
    {
        int s = tid >> 3, seg = tid & 7;
        const float* xr = x + (size_t)(b0 + s) * CIN + seg * 32;
        float p = 0.f;
        #pragma unroll
        for (int k = 0; k < 8; ++k) {
            float4 v = *(const float4*)(xr + k * 4);
            p += v.x + v.y + v.z + v.w;
        }
        red[s][seg] = p;
    }
    // zero cols [330,352)
    for (int idx = tid; idx < 32 * 22; idx += 256) {
        int s = idx / 22, c = 330 + idx % 22;
        As[s * LDA2S + c] = 0;
    }
    // stage Bs: 64 rows x 352
    #pragma unroll
    for (int it = 0; it < 11; ++it) {
        int idx = it * 256 + tid;
        int r = idx / 44, c = (idx % 44) * 8;
        *(uint4*)&Bs[r * LDB2S + c] =
            *(const uint4*)(B2 + (size_t)(n0 + r) * K2 + c);
    }
    // fold t[s][m] into As cols [256,320)
    {
        int s = tid >> 3, mg = tid & 7;
        const unsigned short* grow = G + (size_t)(b0 + s) * LDG;
        float4 h0 = *(const float4*)(h + (size_t)(b0 + s) * NP);
        float4 h1 = *(const float4*)(h + (size_t)(b0 + s) * NP + 4);
        float hv[8] = {h0.x, h0.y, h0.z, h0.w, h1.x, h1.y, h1.z, h1.w};
        ushort4 cu0 = *(const ushort4*)(grow + 512 + mg * 8);
        ushort4 cu1 = *(const ushort4*)(grow + 512 + mg * 8 + 4);
        float t[8] = {bf2f(cu0.x), bf2f(cu0.y), bf2f(cu0.z), bf2f(cu0.w),
                      bf2f(cu1.x), bf2f(cu1.y), bf2f(cu1.z), bf2f(cu1.w)};
        #pragma unroll
        for (int j = 0; j < 8; ++j) {
            const unsigned short* gp = grow + (mg * 8 + j) * 8;
            ushort4 g0 = *(const ushort4*)gp;
            ushort4 g1 = *(const ushort4*)(gp + 4);
            t[j] += hv[0] * bf2f(g0.x) + hv[1] * bf2f(g0.y)
                  + hv[2] * bf2f(g0.z) + hv[3] * bf2f(g0.w)
                  + hv[4] * bf2f(g1.x) + hv[5] * bf2f(g1.y)
                  + hv[6] * bf2f(g1.z) + hv[7] * bf2f(g1.w);
        }
        ushort4 t0, t1;
        t0.x = f2bf(t[0]); t0.y = f2bf(t[1]); t0.z = f2bf(t[2]); t0.w = f2bf(t[3]);
        t1.x = f2bf(t[4]); t1.y = f2bf(t[5]); t1.z = f2bf(t[6]); t1.w = f2bf(t[7]);
        *(ushort4*)&As[s * LDA2S + 256 + mg * 8]     = t0;
        *(ushort4*)&As[s * LDA2S + 256 + mg * 8 + 4] = t1;
    }
    __syncthreads();
    // sx + ones into As cols 328/329
    if (tid < 32) {
        float s = red[tid][0] + red[tid][1] + red[tid][2] + red[tid][3]
                + red[tid][4] + red[tid][5] + red[tid][6] + red[tid][7];
        As[tid * LDA2S + 328] = f2bf(s);
        As[tid * LDA2S + 329] = 0x3F80;   // 1.0 bf16
    }
    __syncthreads();

    const int mr = (w & 1) * 16, nbw = (w >> 1) * 32;
    floatx4 acc[2] = {floatx4{0,0,0,0}, floatx4{0,0,0,0}};
    #pragma unroll
    for (int ks = 0; ks < 11; ++ks) {
        int kc = ks * 32 + quad * 8;
        short8 af = *(const short8*)&As[(mr + col) * LDA2S + kc];
        #pragma unroll
        for (int f = 0; f < 2; ++f) {
            short8 bfr = *(const short8*)&Bs[(nbw + f * 16 + col) * LDB2S + kc];
            acc[f] = __builtin_amdgcn_mfma_f32_16x16x32_bf16(af, bfr, acc[f], 0, 0, 0);
        }
    }
    #pragma unroll
    for (int f = 0; f < 2; ++f)
        #pragma unroll
        for (int r = 0; r < 4; ++r)
            out[(size_t)(b0 + mr + quad * 4 + r) * COUT + n0 + nbw + f * 16 + col]
                = acc[f][r];
}

extern "C" void kernel_launch(void* const* d_in, const int* in_sizes, int n_in,
                              void* d_out, int out_size, void* d_ws, size_t ws_size,
                              hipStream_t stream) {
    const float* x        = (const float*)d_in[0];
    const float* h        = (const float*)d_in[1];
    const float* index    = (const float*)d_in[2];
    const float* target_w = (const float*)d_in[3];
    const float* target_b = (const float*)d_in[4];
    const float* fcwp_w   = (const float*)d_in[5];
    const float* fcwp_b   = (const float*)d_in[6];
    const float* fcwi_w   = (const float*)d_in[7];
    const float* fcwi_b   = (const float*)d_in[8];
    const float* fcwe_w   = (const float*)d_in[9];
    const float* fcwe_b   = (const float*)d_in[10];
    const float* fcbp_w   = (const float*)d_in[11];
    const float* fcbp_b   = (const float*)d_in[12];
    const float* fcbi_w   = (const float*)d_in[13];
    const float* fcbi_b   = (const float*)d_in[14];
    float* out = (float*)d_out;

    char* ws = (char*)d_ws;
    unsigned short* Bb = (unsigned short*)ws;               // 576*256*2 = 294912
    unsigned short* B2 = (unsigned short*)(ws + 294912);    // 256*352*2 = 180224
    unsigned short* G  = (unsigned short*)(ws + 475136);    // 2048*576*2 = 2359296

    setup_bb<<<36, 256, 0, stream>>>(index, fcwp_w, fcwp_b, fcwi_w, fcwi_b, Bb);

    gemm1_kernel<<<309, 256, 0, stream>>>(
        x, Bb, index, target_w, target_b, fcwe_w, fcwe_b,
        fcbp_w, fcbp_b, fcbi_w, fcbi_b, B2, G);

    gemm2_kernel<<<dim3(B_TOT / 32, COUT / 64), 256, 0, stream>>>(
        x, h, B2, G, out);
}